// Round 2
// baseline (5170.347 us; speedup 1.0000x reference)
//
#include <hip/hip_runtime.h>

#define N_NODES   20000
#define N_EDGES   160000
#define IN_DIM    64
#define HID       256
#define EDGE_DIM  64
#define NUM_GRAPHS 128
#define N_LAYERS  3

// ---------------------------------------------------------------- k_lin
// h = x @ Wlin + blin.  16 nodes per block, 256 threads = 256 cols.
__global__ __launch_bounds__(256) void k_lin(const float* __restrict__ x,
                                             const float* __restrict__ W,
                                             const float* __restrict__ b,
                                             float* __restrict__ h) {
    __shared__ float Xs[16][68];
    const int tid = threadIdx.x;
    const int n0  = blockIdx.x * 16;
    {
        const int row = tid >> 4, q = tid & 15;
        const float4 v = *(const float4*)&x[(size_t)(n0 + row) * IN_DIM + q * 4];
        Xs[row][q * 4 + 0] = v.x; Xs[row][q * 4 + 1] = v.y;
        Xs[row][q * 4 + 2] = v.z; Xs[row][q * 4 + 3] = v.w;
    }
    __syncthreads();
    const int col = tid;
    float acc[16];
    #pragma unroll
    for (int r = 0; r < 16; ++r) acc[r] = 0.f;
    for (int k = 0; k < IN_DIM; ++k) {
        const float w = W[(size_t)k * HID + col];
        #pragma unroll
        for (int r = 0; r < 16; ++r) acc[r] += Xs[r][k] * w;
    }
    const float bb = b[col];
    #pragma unroll
    for (int r = 0; r < 16; ++r) h[(size_t)(n0 + r) * HID + col] = acc[r] + bb;
}

// ---------------------------------------------------------------- k_msg
// Fused per-edge MLP + weighted scatter-add.
// Block = 64 edges. Phase1: T = relu(concat @ W1 + b1)  (K = 256|256|64 segs
// + rank-1 sf terms). Phase2: M = T @ W2 + b2; atomicAdd M*ew into upd[no].
__global__ __launch_bounds__(256) void k_msg(const float* __restrict__ h,
                                             const float* __restrict__ sf,
                                             const float* __restrict__ ef,
                                             const float* __restrict__ ew,
                                             const int*   __restrict__ el,
                                             const float* __restrict__ W1,
                                             const float* __restrict__ b1,
                                             const float* __restrict__ W2,
                                             const float* __restrict__ b2,
                                             float* __restrict__ upd) {
    __shared__ float As[64][20];    // 64 rows x 16 K (pad->20, 16B aligned rows)
    __shared__ float Bs[16][256];   // 16 K x 256 cols
    __shared__ float Ts[64][260];   // phase-1 output (pad 260: 1040B rows, 16B aligned)
    __shared__ int   Sni[64], Sno[64];
    __shared__ float Sew[64], Ssa[64], Ssb[64];

    const int tid = threadIdx.x;
    const int e0  = blockIdx.x * 64;
    if (tid < 64) {
        const int e = e0 + tid;
        const int a = el[2 * e], bn = el[2 * e + 1];
        Sni[tid] = a; Sno[tid] = bn;
        Sew[tid] = ew[e];
        Ssa[tid] = sf[a]; Ssb[tid] = sf[bn];
    }
    __syncthreads();

    const int tx = tid & 15;          // col group (16)
    const int ty = tid >> 4;          // row group (16)
    const int colbase = tx * 4;
    const int arow = tid & 63;        // staging row
    const int aq   = tid >> 6;        // staging quad 0..3

    float acc[4][4][4];               // [cc][r][j]
    #pragma unroll
    for (int cc = 0; cc < 4; ++cc)
        #pragma unroll
        for (int r = 0; r < 4; ++r)
            #pragma unroll
            for (int j = 0; j < 4; ++j) acc[cc][r][j] = 0.f;

    // -------- phase 1 : three K segments --------
    for (int seg = 0; seg < 3; ++seg) {
        const int Kseg = (seg == 2) ? EDGE_DIM : HID;
        const float* __restrict__ bsrc =
            W1 + (size_t)(seg == 0 ? 0 : (seg == 1 ? 256 : 514)) * HID;
        for (int k0 = 0; k0 < Kseg; k0 += 16) {
            {   // stage A (gathered rows)
                const float* src;
                if (seg == 0)      src = h  + (size_t)Sni[arow] * HID + k0;
                else if (seg == 1) src = h  + (size_t)Sno[arow] * HID + k0;
                else               src = ef + (size_t)(e0 + arow) * EDGE_DIM + k0;
                const float4 v = *(const float4*)(src + aq * 4);
                *(float4*)&As[arow][aq * 4] = v;
            }
            #pragma unroll
            for (int j = 0; j < 4; ++j) {   // stage B (coalesced)
                const int i  = tid + j * 256;
                const int kk = i >> 6, cq = i & 63;
                *(float4*)&Bs[kk][cq * 4] =
                    *(const float4*)&bsrc[(size_t)(k0 + kk) * HID + cq * 4];
            }
            __syncthreads();
            #pragma unroll
            for (int kk = 0; kk < 16; ++kk) {
                float a[4];
                #pragma unroll
                for (int r = 0; r < 4; ++r) a[r] = As[ty * 4 + r][kk];
                #pragma unroll
                for (int cc = 0; cc < 4; ++cc) {
                    const float4 bv = *(const float4*)&Bs[kk][cc * 64 + colbase];
                    #pragma unroll
                    for (int r = 0; r < 4; ++r) {
                        acc[cc][r][0] += a[r] * bv.x;
                        acc[cc][r][1] += a[r] * bv.y;
                        acc[cc][r][2] += a[r] * bv.z;
                        acc[cc][r][3] += a[r] * bv.w;
                    }
                }
            }
            __syncthreads();
        }
    }

    // rank-1 sf terms + bias + relu -> Ts
    #pragma unroll
    for (int cc = 0; cc < 4; ++cc) {
        const int c = cc * 64 + colbase;
        const float4 w512 = *(const float4*)&W1[(size_t)512 * HID + c];
        const float4 w513 = *(const float4*)&W1[(size_t)513 * HID + c];
        const float4 bv   = *(const float4*)&b1[c];
        #pragma unroll
        for (int r = 0; r < 4; ++r) {
            const int row = ty * 4 + r;
            const float sa = Ssa[row], sb = Ssb[row];
            float4 v;
            v.x = acc[cc][r][0] + sa * w512.x + sb * w513.x + bv.x;
            v.y = acc[cc][r][1] + sa * w512.y + sb * w513.y + bv.y;
            v.z = acc[cc][r][2] + sa * w512.z + sb * w513.z + bv.z;
            v.w = acc[cc][r][3] + sa * w512.w + sb * w513.w + bv.w;
            v.x = v.x > 0.f ? v.x : 0.f;
            v.y = v.y > 0.f ? v.y : 0.f;
            v.z = v.z > 0.f ? v.z : 0.f;
            v.w = v.w > 0.f ? v.w : 0.f;
            *(float4*)&Ts[row][c] = v;
        }
    }
    __syncthreads();

    // -------- phase 2 : M = Ts @ W2 + b2 --------
    float acc2[4][4][4];
    #pragma unroll
    for (int cc = 0; cc < 4; ++cc)
        #pragma unroll
        for (int r = 0; r < 4; ++r)
            #pragma unroll
            for (int j = 0; j < 4; ++j) acc2[cc][r][j] = 0.f;

    for (int k0 = 0; k0 < HID; k0 += 16) {
        #pragma unroll
        for (int j = 0; j < 4; ++j) {
            const int i  = tid + j * 256;
            const int kk = i >> 6, cq = i & 63;
            *(float4*)&Bs[kk][cq * 4] =
                *(const float4*)&W2[(size_t)(k0 + kk) * HID + cq * 4];
        }
        __syncthreads();
        #pragma unroll
        for (int kk = 0; kk < 16; ++kk) {
            float a[4];
            #pragma unroll
            for (int r = 0; r < 4; ++r) a[r] = Ts[ty * 4 + r][k0 + kk];
            #pragma unroll
            for (int cc = 0; cc < 4; ++cc) {
                const float4 bv = *(const float4*)&Bs[kk][cc * 64 + colbase];
                #pragma unroll
                for (int r = 0; r < 4; ++r) {
                    acc2[cc][r][0] += a[r] * bv.x;
                    acc2[cc][r][1] += a[r] * bv.y;
                    acc2[cc][r][2] += a[r] * bv.z;
                    acc2[cc][r][3] += a[r] * bv.w;
                }
            }
        }
        __syncthreads();
    }

    // epilogue: + b2, * ew, atomic scatter into upd[node_out]
    #pragma unroll
    for (int cc = 0; cc < 4; ++cc) {
        const int c = cc * 64 + colbase;
        const float4 b2v = *(const float4*)&b2[c];
        #pragma unroll
        for (int r = 0; r < 4; ++r) {
            const int row = ty * 4 + r;
            const float w = Sew[row];
            float* dst = upd + (size_t)Sno[row] * HID + c;
            atomicAdd(&dst[0], (acc2[cc][r][0] + b2v.x) * w);
            atomicAdd(&dst[1], (acc2[cc][r][1] + b2v.y) * w);
            atomicAdd(&dst[2], (acc2[cc][r][2] + b2v.z) * w);
            atomicAdd(&dst[3], (acc2[cc][r][3] + b2v.w) * w);
        }
    }
}

// ---------------------------------------------------------------- k_upd
// h_out = relu( relu(concat(h,upd) @ W1 + b1) @ W2 + b2 ), 64 nodes/block.
__global__ __launch_bounds__(256) void k_upd(const float* __restrict__ h,
                                             const float* __restrict__ upd,
                                             const float* __restrict__ W1,
                                             const float* __restrict__ b1,
                                             const float* __restrict__ W2,
                                             const float* __restrict__ b2,
                                             float* __restrict__ hout) {
    __shared__ float As[64][20];
    __shared__ float Bs[16][256];
    __shared__ float Ts[64][260];

    const int tid = threadIdx.x;
    const int n0  = blockIdx.x * 64;
    const int tx = tid & 15;
    const int ty = tid >> 4;
    const int colbase = tx * 4;
    const int arow = tid & 63;
    const int aq   = tid >> 6;
    const int nrow = (n0 + arow < N_NODES) ? (n0 + arow) : (N_NODES - 1);

    float acc[4][4][4];
    #pragma unroll
    for (int cc = 0; cc < 4; ++cc)
        #pragma unroll
        for (int r = 0; r < 4; ++r)
            #pragma unroll
            for (int j = 0; j < 4; ++j) acc[cc][r][j] = 0.f;

    for (int seg = 0; seg < 2; ++seg) {
        const float* __restrict__ asrc = (seg == 0) ? h : upd;
        const float* __restrict__ bsrc = W1 + (size_t)(seg * 256) * HID;
        for (int k0 = 0; k0 < HID; k0 += 16) {
            {
                const float4 v = *(const float4*)(asrc + (size_t)nrow * HID + k0 + aq * 4);
                *(float4*)&As[arow][aq * 4] = v;
            }
            #pragma unroll
            for (int j = 0; j < 4; ++j) {
                const int i  = tid + j * 256;
                const int kk = i >> 6, cq = i & 63;
                *(float4*)&Bs[kk][cq * 4] =
                    *(const float4*)&bsrc[(size_t)(k0 + kk) * HID + cq * 4];
            }
            __syncthreads();
            #pragma unroll
            for (int kk = 0; kk < 16; ++kk) {
                float a[4];
                #pragma unroll
                for (int r = 0; r < 4; ++r) a[r] = As[ty * 4 + r][kk];
                #pragma unroll
                for (int cc = 0; cc < 4; ++cc) {
                    const float4 bv = *(const float4*)&Bs[kk][cc * 64 + colbase];
                    #pragma unroll
                    for (int r = 0; r < 4; ++r) {
                        acc[cc][r][0] += a[r] * bv.x;
                        acc[cc][r][1] += a[r] * bv.y;
                        acc[cc][r][2] += a[r] * bv.z;
                        acc[cc][r][3] += a[r] * bv.w;
                    }
                }
            }
            __syncthreads();
        }
    }

    #pragma unroll
    for (int cc = 0; cc < 4; ++cc) {
        const int c = cc * 64 + colbase;
        const float4 bv = *(const float4*)&b1[c];
        #pragma unroll
        for (int r = 0; r < 4; ++r) {
            const int row = ty * 4 + r;
            float4 v;
            v.x = acc[cc][r][0] + bv.x; v.y = acc[cc][r][1] + bv.y;
            v.z = acc[cc][r][2] + bv.z; v.w = acc[cc][r][3] + bv.w;
            v.x = v.x > 0.f ? v.x : 0.f; v.y = v.y > 0.f ? v.y : 0.f;
            v.z = v.z > 0.f ? v.z : 0.f; v.w = v.w > 0.f ? v.w : 0.f;
            *(float4*)&Ts[row][c] = v;
        }
    }
    __syncthreads();

    float acc2[4][4][4];
    #pragma unroll
    for (int cc = 0; cc < 4; ++cc)
        #pragma unroll
        for (int r = 0; r < 4; ++r)
            #pragma unroll
            for (int j = 0; j < 4; ++j) acc2[cc][r][j] = 0.f;

    for (int k0 = 0; k0 < HID; k0 += 16) {
        #pragma unroll
        for (int j = 0; j < 4; ++j) {
            const int i  = tid + j * 256;
            const int kk = i >> 6, cq = i & 63;
            *(float4*)&Bs[kk][cq * 4] =
                *(const float4*)&W2[(size_t)(k0 + kk) * HID + cq * 4];
        }
        __syncthreads();
        #pragma unroll
        for (int kk = 0; kk < 16; ++kk) {
            float a[4];
            #pragma unroll
            for (int r = 0; r < 4; ++r) a[r] = Ts[ty * 4 + r][k0 + kk];
            #pragma unroll
            for (int cc = 0; cc < 4; ++cc) {
                const float4 bv = *(const float4*)&Bs[kk][cc * 64 + colbase];
                #pragma unroll
                for (int r = 0; r < 4; ++r) {
                    acc2[cc][r][0] += a[r] * bv.x;
                    acc2[cc][r][1] += a[r] * bv.y;
                    acc2[cc][r][2] += a[r] * bv.z;
                    acc2[cc][r][3] += a[r] * bv.w;
                }
            }
        }
        __syncthreads();
    }

    #pragma unroll
    for (int cc = 0; cc < 4; ++cc) {
        const int c = cc * 64 + colbase;
        const float4 bv = *(const float4*)&b2[c];
        #pragma unroll
        for (int r = 0; r < 4; ++r) {
            const int row = ty * 4 + r;
            if (n0 + row >= N_NODES) continue;
            float4 v;
            v.x = acc2[cc][r][0] + bv.x; v.y = acc2[cc][r][1] + bv.y;
            v.z = acc2[cc][r][2] + bv.z; v.w = acc2[cc][r][3] + bv.w;
            v.x = v.x > 0.f ? v.x : 0.f; v.y = v.y > 0.f ? v.y : 0.f;
            v.z = v.z > 0.f ? v.z : 0.f; v.w = v.w > 0.f ? v.w : 0.f;
            *(float4*)&hout[(size_t)(n0 + row) * HID + c] = v;
        }
    }
}

// ---------------------------------------------------------------- k_graph
// node2graph is sorted: run-length accumulate, flush on segment change.
__global__ __launch_bounds__(256) void k_graph(const float* __restrict__ h,
                                               const int* __restrict__ n2g,
                                               float* __restrict__ out) {
    __shared__ int Sg[64];
    const int tid = threadIdx.x;
    const int n0  = blockIdx.x * 64;
    if (tid < 64) {
        const int n = n0 + tid;
        Sg[tid] = (n < N_NODES) ? n2g[n] : -1;
    }
    __syncthreads();
    const int col = tid;
    float accv = 0.f;
    int curg = Sg[0];
    for (int r = 0; r < 64; ++r) {
        const int n = n0 + r;
        if (n >= N_NODES) break;
        const int g = Sg[r];
        if (g != curg) {
            atomicAdd(&out[(size_t)curg * HID + col], accv);
            accv = 0.f; curg = g;
        }
        accv += h[(size_t)n * HID + col];
    }
    atomicAdd(&out[(size_t)curg * HID + col], accv);
}

// ---------------------------------------------------------------- launch
extern "C" void kernel_launch(void* const* d_in, const int* in_sizes, int n_in,
                              void* d_out, int out_size, void* d_ws, size_t ws_size,
                              hipStream_t stream) {
    const float* x    = (const float*)d_in[0];
    const float* sf   = (const float*)d_in[1];
    const float* ef   = (const float*)d_in[2];
    const float* ew   = (const float*)d_in[3];
    const int*   el   = (const int*)d_in[4];
    const int*   n2g  = (const int*)d_in[5];
    const float* Wlin = (const float*)d_in[6];
    const float* blin = (const float*)d_in[7];
    const float* mW1  = (const float*)d_in[8];
    const float* mb1  = (const float*)d_in[9];
    const float* mW2  = (const float*)d_in[10];
    const float* mb2  = (const float*)d_in[11];
    const float* uW1  = (const float*)d_in[12];
    const float* ub1  = (const float*)d_in[13];
    const float* uW2  = (const float*)d_in[14];
    const float* ub2  = (const float*)d_in[15];
    float* out = (float*)d_out;

    float* hA  = (float*)d_ws;                     // N_NODES*HID
    float* hB  = hA + (size_t)N_NODES * HID;       // N_NODES*HID
    float* upd = hB + (size_t)N_NODES * HID;       // N_NODES*HID

    hipMemsetAsync(d_out, 0, (size_t)NUM_GRAPHS * HID * sizeof(float), stream);

    k_lin<<<N_NODES / 16, 256, 0, stream>>>(x, Wlin, blin, hA);

    float* hc = hA;
    float* hn = hB;
    for (int l = 0; l < N_LAYERS; ++l) {
        hipMemsetAsync(upd, 0, (size_t)N_NODES * HID * sizeof(float), stream);
        const int MSG_IN = 2 * HID + 2 + EDGE_DIM;  // 578
        k_msg<<<N_EDGES / 64, 256, 0, stream>>>(
            hc, sf, ef, ew, el,
            mW1 + (size_t)l * MSG_IN * HID, mb1 + (size_t)l * HID,
            mW2 + (size_t)l * HID * HID,   mb2 + (size_t)l * HID, upd);
        k_upd<<<(N_NODES + 63) / 64, 256, 0, stream>>>(
            hc, upd,
            uW1 + (size_t)l * 2 * HID * HID, ub1 + (size_t)l * HID,
            uW2 + (size_t)l * HID * HID,     ub2 + (size_t)l * HID, hn);
        float* t = hc; hc = hn; hn = t;
    }

    k_graph<<<(N_NODES + 63) / 64, 256, 0, stream>>>(hc, n2g, out);
}

// Round 3
// 881.209 us; speedup vs baseline: 5.8673x; 5.8673x over previous
//
#include <hip/hip_runtime.h>
#include <hip/hip_bf16.h>

#define N_NODES   20000
#define N_EDGES   160000
#define IN_DIM    64
#define HID       256
#define EDGE_DIM  64
#define NUM_GRAPHS 128
#define N_LAYERS  3

typedef __attribute__((ext_vector_type(8))) short s16x8;
typedef __attribute__((ext_vector_type(4))) float f32x4;

static __device__ __forceinline__ unsigned short f2bu(float f) {
    union { __hip_bfloat16 h; unsigned short u; } cv;
    cv.h = __float2bfloat16(f);
    return cv.u;
}
static __device__ __forceinline__ s16x8 pack8(const float4 a, const float4 b) {
    s16x8 p;
    p[0] = (short)f2bu(a.x); p[1] = (short)f2bu(a.y);
    p[2] = (short)f2bu(a.z); p[3] = (short)f2bu(a.w);
    p[4] = (short)f2bu(b.x); p[5] = (short)f2bu(b.y);
    p[6] = (short)f2bu(b.z); p[7] = (short)f2bu(b.w);
    return p;
}

// Weight tile geometry: each K-step tile is [256 cols][32 k] bf16 = 8192 shorts.
#define TILE_SH 8192

// ---------------------------------------------------------------- k_prep
// Convert fp32 weights -> bf16 K-step tiles, K-contiguous per output col.
// 50 tiles per layer: msg1(18: k 0..511 = h|h, 16..17 = W1 rows 514..577),
// msg2(8), upd1(16), upd2(8).
__global__ __launch_bounds__(256) void k_prep(const float* __restrict__ mW1,
                                              const float* __restrict__ mW2,
                                              const float* __restrict__ uW1,
                                              const float* __restrict__ uW2,
                                              unsigned short* __restrict__ msgW1T,
                                              unsigned short* __restrict__ msgW2T,
                                              unsigned short* __restrict__ updW1T,
                                              unsigned short* __restrict__ updW2T) {
    const int b = blockIdx.x;
    const int l = b / 50, t = b % 50;
    const float* W; unsigned short* dst; int rowbase;
    if (t < 18) {
        W = mW1 + (size_t)l * 578 * 256;
        dst = msgW1T + ((size_t)l * 18 + t) * TILE_SH;
        rowbase = (t < 16) ? t * 32 : 514 + (t - 16) * 32;
    } else if (t < 26) {
        const int tt = t - 18;
        W = mW2 + (size_t)l * 65536;
        dst = msgW2T + ((size_t)l * 8 + tt) * TILE_SH;
        rowbase = tt * 32;
    } else if (t < 42) {
        const int tt = t - 26;
        W = uW1 + (size_t)l * 131072;
        dst = updW1T + ((size_t)l * 16 + tt) * TILE_SH;
        rowbase = tt * 32;
    } else {
        const int tt = t - 42;
        W = uW2 + (size_t)l * 65536;
        dst = updW2T + ((size_t)l * 8 + tt) * TILE_SH;
        rowbase = tt * 32;
    }
    const int c = threadIdx.x;
    unsigned short buf[32];
    #pragma unroll
    for (int kk = 0; kk < 32; ++kk)
        buf[kk] = f2bu(W[(size_t)(rowbase + kk) * 256 + c]);
    #pragma unroll
    for (int j = 0; j < 4; ++j)
        *(s16x8*)&dst[(size_t)c * 32 + j * 8] = *(const s16x8*)&buf[j * 8];
}

// ---------------------------------------------------------------- k_lin
__global__ __launch_bounds__(256) void k_lin(const float* __restrict__ x,
                                             const float* __restrict__ W,
                                             const float* __restrict__ b,
                                             float* __restrict__ h) {
    __shared__ float Xs[16][68];
    const int tid = threadIdx.x;
    const int n0  = blockIdx.x * 16;
    {
        const int row = tid >> 4, q = tid & 15;
        const float4 v = *(const float4*)&x[(size_t)(n0 + row) * IN_DIM + q * 4];
        Xs[row][q * 4 + 0] = v.x; Xs[row][q * 4 + 1] = v.y;
        Xs[row][q * 4 + 2] = v.z; Xs[row][q * 4 + 3] = v.w;
    }
    __syncthreads();
    const int col = tid;
    float acc[16];
    #pragma unroll
    for (int r = 0; r < 16; ++r) acc[r] = 0.f;
    for (int k = 0; k < IN_DIM; ++k) {
        const float w = W[(size_t)k * HID + col];
        #pragma unroll
        for (int r = 0; r < 16; ++r) acc[r] += Xs[r][k] * w;
    }
    const float bb = b[col];
    #pragma unroll
    for (int r = 0; r < 16; ++r) h[(size_t)(n0 + r) * HID + col] = acc[r] + bb;
}

// ---------------------------------------------------------------- k_msg (MFMA)
// 64 edges x 256 cols per block. 4 waves; wave w owns cols [w*64, w*64+64).
// GEMM1: K = 512 (h[ni]|h[no]) + 64 (ef) in 18 steps of 32; sf rank-1 + bias
// + relu in fp32 epilogue -> Ts (bf16). GEMM2: K=256 in 8 steps; *ew; atomic
// scatter into upd[node_out].
__global__ __launch_bounds__(256, 2) void k_msg(const float* __restrict__ h,
                                                const float* __restrict__ sf,
                                                const float* __restrict__ ef,
                                                const float* __restrict__ ew,
                                                const int*   __restrict__ el,
                                                const unsigned short* __restrict__ W1T,
                                                const float* __restrict__ W1f,
                                                const float* __restrict__ b1,
                                                const unsigned short* __restrict__ W2T,
                                                const float* __restrict__ b2,
                                                float* __restrict__ upd) {
    __shared__ unsigned short As[64 * 40];    // A tile, rows padded to 40
    __shared__ unsigned short Bs[256 * 40];   // B tile, cols padded to 40
    __shared__ unsigned short Ts[64 * 264];   // GEMM1 output (bf16)
    __shared__ int   Sni[64], Sno[64];
    __shared__ float Sew[64], Ssa[64], Ssb[64];

    const int tid = threadIdx.x;
    const int e0  = blockIdx.x * 64;
    if (tid < 64) {
        const int e = e0 + tid;
        const int a = el[2 * e], bn = el[2 * e + 1];
        Sni[tid] = a; Sno[tid] = bn;
        Sew[tid] = ew[e]; Ssa[tid] = sf[a]; Ssb[tid] = sf[bn];
    }
    __syncthreads();

    const int lane = tid & 63, wv = tid >> 6;
    const int lr = lane & 15, lq = lane >> 4;
    const int arow = tid & 63, aq = tid >> 6;
    const int ni = Sni[arow], no = Sno[arow];

    f32x4 acc[4][4];
    #pragma unroll
    for (int i = 0; i < 4; ++i)
        #pragma unroll
        for (int j = 0; j < 4; ++j) acc[i][j] = (f32x4)(0.0f);

    // ---------------- GEMM1 ----------------
    for (int s = 0; s < 18; ++s) {
        const float* asrc;
        if (s < 8)       asrc = h  + (size_t)ni * HID + s * 32;
        else if (s < 16) asrc = h  + (size_t)no * HID + (s - 8) * 32;
        else             asrc = ef + (size_t)(e0 + arow) * EDGE_DIM + (s - 16) * 32;
        __syncthreads();
        {   // stage A (fp32 gather -> bf16)
            const float4 v0 = *(const float4*)(asrc + aq * 8);
            const float4 v1 = *(const float4*)(asrc + aq * 8 + 4);
            *(s16x8*)&As[arow * 40 + aq * 8] = pack8(v0, v1);
        }
        {   // stage B (bf16 tiles, coalesced)
            const s16x8* src = (const s16x8*)(W1T + (size_t)s * TILE_SH + tid * 32);
            unsigned short* dst = &Bs[tid * 40];
            *(s16x8*)&dst[0]  = src[0];
            *(s16x8*)&dst[8]  = src[1];
            *(s16x8*)&dst[16] = src[2];
            *(s16x8*)&dst[24] = src[3];
        }
        __syncthreads();
        s16x8 af[4], bf[4];
        #pragma unroll
        for (int mf = 0; mf < 4; ++mf)
            af[mf] = *(const s16x8*)&As[(mf * 16 + lr) * 40 + lq * 8];
        #pragma unroll
        for (int nf = 0; nf < 4; ++nf)
            bf[nf] = *(const s16x8*)&Bs[(wv * 64 + nf * 16 + lr) * 40 + lq * 8];
        #pragma unroll
        for (int mf = 0; mf < 4; ++mf)
            #pragma unroll
            for (int nf = 0; nf < 4; ++nf)
                acc[mf][nf] = __builtin_amdgcn_mfma_f32_16x16x32_bf16(
                    af[mf], bf[nf], acc[mf][nf], 0, 0, 0);
    }

    // epilogue 1: sf rank-1 + bias + relu -> Ts (bf16)
    #pragma unroll
    for (int nf = 0; nf < 4; ++nf) {
        const int col = wv * 64 + nf * 16 + lr;
        const float w512 = W1f[(size_t)512 * HID + col];
        const float w513 = W1f[(size_t)513 * HID + col];
        const float bb   = b1[col];
        #pragma unroll
        for (int mf = 0; mf < 4; ++mf)
            #pragma unroll
            for (int r = 0; r < 4; ++r) {
                const int row = mf * 16 + lq * 4 + r;
                float v = acc[mf][nf][r] + Ssa[row] * w512 + Ssb[row] * w513 + bb;
                v = fmaxf(v, 0.f);
                Ts[row * 264 + col] = f2bu(v);
            }
    }

    // ---------------- GEMM2 ----------------
    f32x4 acc2[4][4];
    #pragma unroll
    for (int i = 0; i < 4; ++i)
        #pragma unroll
        for (int j = 0; j < 4; ++j) acc2[i][j] = (f32x4)(0.0f);

    for (int s = 0; s < 8; ++s) {
        __syncthreads();
        {
            const s16x8* src = (const s16x8*)(W2T + (size_t)s * TILE_SH + tid * 32);
            unsigned short* dst = &Bs[tid * 40];
            *(s16x8*)&dst[0]  = src[0];
            *(s16x8*)&dst[8]  = src[1];
            *(s16x8*)&dst[16] = src[2];
            *(s16x8*)&dst[24] = src[3];
        }
        __syncthreads();
        s16x8 af[4], bf[4];
        #pragma unroll
        for (int mf = 0; mf < 4; ++mf)
            af[mf] = *(const s16x8*)&Ts[(mf * 16 + lr) * 264 + s * 32 + lq * 8];
        #pragma unroll
        for (int nf = 0; nf < 4; ++nf)
            bf[nf] = *(const s16x8*)&Bs[(wv * 64 + nf * 16 + lr) * 40 + lq * 8];
        #pragma unroll
        for (int mf = 0; mf < 4; ++mf)
            #pragma unroll
            for (int nf = 0; nf < 4; ++nf)
                acc2[mf][nf] = __builtin_amdgcn_mfma_f32_16x16x32_bf16(
                    af[mf], bf[nf], acc2[mf][nf], 0, 0, 0);
    }

    // epilogue 2: + b2, * ew, atomic scatter
    #pragma unroll
    for (int nf = 0; nf < 4; ++nf) {
        const int col = wv * 64 + nf * 16 + lr;
        const float bb = b2[col];
        #pragma unroll
        for (int mf = 0; mf < 4; ++mf)
            #pragma unroll
            for (int r = 0; r < 4; ++r) {
                const int row = mf * 16 + lq * 4 + r;
                const float v = (acc2[mf][nf][r] + bb) * Sew[row];
                atomicAdd(&upd[(size_t)Sno[row] * HID + col], v);
            }
    }
}

// ---------------------------------------------------------------- k_upd (MFMA)
// 64 nodes x 256 cols per block; K = 512 (h|upd) in 16 steps; relu -> Ts;
// GEMM2 K=256; relu; direct store.
__global__ __launch_bounds__(256, 2) void k_upd(const float* __restrict__ h,
                                                const float* __restrict__ upd,
                                                const unsigned short* __restrict__ W1T,
                                                const float* __restrict__ b1,
                                                const unsigned short* __restrict__ W2T,
                                                const float* __restrict__ b2,
                                                float* __restrict__ hout) {
    __shared__ unsigned short As[64 * 40];
    __shared__ unsigned short Bs[256 * 40];
    __shared__ unsigned short Ts[64 * 264];

    const int tid = threadIdx.x;
    const int n0  = blockIdx.x * 64;
    const int lane = tid & 63, wv = tid >> 6;
    const int lr = lane & 15, lq = lane >> 4;
    const int arow = tid & 63, aq = tid >> 6;
    const int node = (n0 + arow < N_NODES) ? (n0 + arow) : (N_NODES - 1);

    f32x4 acc[4][4];
    #pragma unroll
    for (int i = 0; i < 4; ++i)
        #pragma unroll
        for (int j = 0; j < 4; ++j) acc[i][j] = (f32x4)(0.0f);

    for (int s = 0; s < 16; ++s) {
        const float* asrc = (s < 8) ? h   + (size_t)node * HID + s * 32
                                    : upd + (size_t)node * HID + (s - 8) * 32;
        __syncthreads();
        {
            const float4 v0 = *(const float4*)(asrc + aq * 8);
            const float4 v1 = *(const float4*)(asrc + aq * 8 + 4);
            *(s16x8*)&As[arow * 40 + aq * 8] = pack8(v0, v1);
        }
        {
            const s16x8* src = (const s16x8*)(W1T + (size_t)s * TILE_SH + tid * 32);
            unsigned short* dst = &Bs[tid * 40];
            *(s16x8*)&dst[0]  = src[0];
            *(s16x8*)&dst[8]  = src[1];
            *(s16x8*)&dst[16] = src[2];
            *(s16x8*)&dst[24] = src[3];
        }
        __syncthreads();
        s16x8 af[4], bf[4];
        #pragma unroll
        for (int mf = 0; mf < 4; ++mf)
            af[mf] = *(const s16x8*)&As[(mf * 16 + lr) * 40 + lq * 8];
        #pragma unroll
        for (int nf = 0; nf < 4; ++nf)
            bf[nf] = *(const s16x8*)&Bs[(wv * 64 + nf * 16 + lr) * 40 + lq * 8];
        #pragma unroll
        for (int mf = 0; mf < 4; ++mf)
            #pragma unroll
            for (int nf = 0; nf < 4; ++nf)
                acc[mf][nf] = __builtin_amdgcn_mfma_f32_16x16x32_bf16(
                    af[mf], bf[nf], acc[mf][nf], 0, 0, 0);
    }

    #pragma unroll
    for (int nf = 0; nf < 4; ++nf) {
        const int col = wv * 64 + nf * 16 + lr;
        const float bb = b1[col];
        #pragma unroll
        for (int mf = 0; mf < 4; ++mf)
            #pragma unroll
            for (int r = 0; r < 4; ++r) {
                const int row = mf * 16 + lq * 4 + r;
                float v = acc[mf][nf][r] + bb;
                v = fmaxf(v, 0.f);
                Ts[row * 264 + col] = f2bu(v);
            }
    }

    f32x4 acc2[4][4];
    #pragma unroll
    for (int i = 0; i < 4; ++i)
        #pragma unroll
        for (int j = 0; j < 4; ++j) acc2[i][j] = (f32x4)(0.0f);

    for (int s = 0; s < 8; ++s) {
        __syncthreads();
        {
            const s16x8* src = (const s16x8*)(W2T + (size_t)s * TILE_SH + tid * 32);
            unsigned short* dst = &Bs[tid * 40];
            *(s16x8*)&dst[0]  = src[0];
            *(s16x8*)&dst[8]  = src[1];
            *(s16x8*)&dst[16] = src[2];
            *(s16x8*)&dst[24] = src[3];
        }
        __syncthreads();
        s16x8 af[4], bf[4];
        #pragma unroll
        for (int mf = 0; mf < 4; ++mf)
            af[mf] = *(const s16x8*)&Ts[(mf * 16 + lr) * 264 + s * 32 + lq * 8];
        #pragma unroll
        for (int nf = 0; nf < 4; ++nf)
            bf[nf] = *(const s16x8*)&Bs[(wv * 64 + nf * 16 + lr) * 40 + lq * 8];
        #pragma unroll
        for (int mf = 0; mf < 4; ++mf)
            #pragma unroll
            for (int nf = 0; nf < 4; ++nf)
                acc2[mf][nf] = __builtin_amdgcn_mfma_f32_16x16x32_bf16(
                    af[mf], bf[nf], acc2[mf][nf], 0, 0, 0);
    }

    #pragma unroll
    for (int nf = 0; nf < 4; ++nf) {
        const int col = wv * 64 + nf * 16 + lr;
        const float bb = b2[col];
        #pragma unroll
        for (int mf = 0; mf < 4; ++mf)
            #pragma unroll
            for (int r = 0; r < 4; ++r) {
                const int row = mf * 16 + lq * 4 + r;
                const int n = n0 + row;
                if (n < N_NODES)
                    hout[(size_t)n * HID + col] = fmaxf(acc2[mf][nf][r] + bb, 0.f);
            }
    }
}

// ---------------------------------------------------------------- k_graph
__global__ __launch_bounds__(256) void k_graph(const float* __restrict__ h,
                                               const int* __restrict__ n2g,
                                               float* __restrict__ out) {
    __shared__ int Sg[64];
    const int tid = threadIdx.x;
    const int n0  = blockIdx.x * 64;
    if (tid < 64) {
        const int n = n0 + tid;
        Sg[tid] = (n < N_NODES) ? n2g[n] : -1;
    }
    __syncthreads();
    const int col = tid;
    float accv = 0.f;
    int curg = Sg[0];
    for (int r = 0; r < 64; ++r) {
        const int n = n0 + r;
        if (n >= N_NODES) break;
        const int g = Sg[r];
        if (g != curg) {
            atomicAdd(&out[(size_t)curg * HID + col], accv);
            accv = 0.f; curg = g;
        }
        accv += h[(size_t)n * HID + col];
    }
    atomicAdd(&out[(size_t)curg * HID + col], accv);
}

// ---------------------------------------------------------------- launch
extern "C" void kernel_launch(void* const* d_in, const int* in_sizes, int n_in,
                              void* d_out, int out_size, void* d_ws, size_t ws_size,
                              hipStream_t stream) {
    const float* x    = (const float*)d_in[0];
    const float* sf   = (const float*)d_in[1];
    const float* ef   = (const float*)d_in[2];
    const float* ew   = (const float*)d_in[3];
    const int*   el   = (const int*)d_in[4];
    const int*   n2g  = (const int*)d_in[5];
    const float* Wlin = (const float*)d_in[6];
    const float* blin = (const float*)d_in[7];
    const float* mW1  = (const float*)d_in[8];
    const float* mb1  = (const float*)d_in[9];
    const float* mW2  = (const float*)d_in[10];
    const float* mb2  = (const float*)d_in[11];
    const float* uW1  = (const float*)d_in[12];
    const float* ub1  = (const float*)d_in[13];
    const float* uW2  = (const float*)d_in[14];
    const float* ub2  = (const float*)d_in[15];
    float* out = (float*)d_out;

    float* hA  = (float*)d_ws;                     // N_NODES*HID
    float* hB  = hA + (size_t)N_NODES * HID;
    float* upd = hB + (size_t)N_NODES * HID;
    unsigned short* wb = (unsigned short*)((char*)d_ws + (size_t)3 * N_NODES * HID * 4);
    unsigned short* msgW1T = wb;                                   // 3*18*8192
    unsigned short* msgW2T = msgW1T + (size_t)3 * 18 * TILE_SH;    // 3*8*8192
    unsigned short* updW1T = msgW2T + (size_t)3 * 8  * TILE_SH;    // 3*16*8192
    unsigned short* updW2T = updW1T + (size_t)3 * 16 * TILE_SH;    // 3*8*8192

    hipMemsetAsync(d_out, 0, (size_t)NUM_GRAPHS * HID * sizeof(float), stream);

    k_prep<<<150, 256, 0, stream>>>(mW1, mW2, uW1, uW2,
                                    msgW1T, msgW2T, updW1T, updW2T);
    k_lin<<<N_NODES / 16, 256, 0, stream>>>(x, Wlin, blin, hA);

    float* hc = hA;
    float* hn = hB;
    for (int l = 0; l < N_LAYERS; ++l) {
        hipMemsetAsync(upd, 0, (size_t)N_NODES * HID * sizeof(float), stream);
        k_msg<<<N_EDGES / 64, 256, 0, stream>>>(
            hc, sf, ef, ew, el,
            msgW1T + (size_t)l * 18 * TILE_SH,
            mW1 + (size_t)l * 578 * 256, mb1 + (size_t)l * HID,
            msgW2T + (size_t)l * 8 * TILE_SH, mb2 + (size_t)l * HID, upd);
        k_upd<<<(N_NODES + 63) / 64, 256, 0, stream>>>(
            hc, upd,
            updW1T + (size_t)l * 16 * TILE_SH, ub1 + (size_t)l * HID,
            updW2T + (size_t)l * 8 * TILE_SH,  ub2 + (size_t)l * HID, hn);
        float* t = hc; hc = hn; hn = t;
    }

    k_graph<<<(N_NODES + 63) / 64, 256, 0, stream>>>(hc, n2g, out);
}

// Round 4
// 716.965 us; speedup vs baseline: 7.2114x; 1.2291x over previous
//
#include <hip/hip_runtime.h>
#include <hip/hip_bf16.h>

#define N_NODES   20000
#define N_EDGES   160000
#define IN_DIM    64
#define HID       256
#define EDGE_DIM  64
#define NUM_GRAPHS 128
#define N_LAYERS  3

typedef __attribute__((ext_vector_type(8))) short s16x8;
typedef __attribute__((ext_vector_type(4))) float f32x4;

static __device__ __forceinline__ unsigned short f2bu(float f) {
    union { __hip_bfloat16 h; unsigned short u; } cv;
    cv.h = __float2bfloat16(f);
    return cv.u;
}
static __device__ __forceinline__ s16x8 pack8(const float4 a, const float4 b) {
    s16x8 p;
    p[0] = (short)f2bu(a.x); p[1] = (short)f2bu(a.y);
    p[2] = (short)f2bu(a.z); p[3] = (short)f2bu(a.w);
    p[4] = (short)f2bu(b.x); p[5] = (short)f2bu(b.y);
    p[6] = (short)f2bu(b.z); p[7] = (short)f2bu(b.w);
    return p;
}

#define TILE_SH 8192   // [256 cols][32 k] bf16

// ---------------------------------------------------------------- sort kernels
__global__ __launch_bounds__(256) void k_deg(const int* __restrict__ el,
                                             int* __restrict__ deg) {
    const int e = blockIdx.x * 256 + threadIdx.x;
    if (e < N_EDGES) atomicAdd(&deg[el[2 * e + 1]], 1);
}

__global__ __launch_bounds__(256) void k_scan(const int* __restrict__ deg,
                                              int* __restrict__ off,
                                              int* __restrict__ cursor) {
    __shared__ int ts[256];
    const int t = threadIdx.x;
    const int base = t * 79;
    const int end  = (base + 79 < N_NODES) ? base + 79 : N_NODES;
    int s = 0;
    for (int i = base; i < end; ++i) s += deg[i];
    ts[t] = s;
    __syncthreads();
    for (int d = 1; d < 256; d <<= 1) {
        const int u = (t >= d) ? ts[t - d] : 0;
        __syncthreads();
        ts[t] += u;
        __syncthreads();
    }
    int run = (t == 0) ? 0 : ts[t - 1];
    for (int i = base; i < end; ++i) {
        off[i] = run; cursor[i] = run; run += deg[i];
    }
}

__global__ __launch_bounds__(256) void k_scat(const int* __restrict__ el,
                                              int* __restrict__ cursor,
                                              int* __restrict__ eidx) {
    const int e = blockIdx.x * 256 + threadIdx.x;
    if (e < N_EDGES) {
        const int d = el[2 * e + 1];
        const int p = atomicAdd(&cursor[d], 1);
        eidx[p] = e;
    }
}

// ---------------------------------------------------------------- k_prep
__global__ __launch_bounds__(256) void k_prep(const float* __restrict__ mW1,
                                              const float* __restrict__ mW2,
                                              const float* __restrict__ uW1,
                                              const float* __restrict__ uW2,
                                              unsigned short* __restrict__ msgW1T,
                                              unsigned short* __restrict__ msgW2T,
                                              unsigned short* __restrict__ updW1T,
                                              unsigned short* __restrict__ updW2T) {
    const int b = blockIdx.x;
    const int l = b / 50, t = b % 50;
    const float* W; unsigned short* dst; int rowbase;
    if (t < 18) {
        W = mW1 + (size_t)l * 578 * 256;
        dst = msgW1T + ((size_t)l * 18 + t) * TILE_SH;
        rowbase = (t < 16) ? t * 32 : 514 + (t - 16) * 32;
    } else if (t < 26) {
        const int tt = t - 18;
        W = mW2 + (size_t)l * 65536;
        dst = msgW2T + ((size_t)l * 8 + tt) * TILE_SH;
        rowbase = tt * 32;
    } else if (t < 42) {
        const int tt = t - 26;
        W = uW1 + (size_t)l * 131072;
        dst = updW1T + ((size_t)l * 16 + tt) * TILE_SH;
        rowbase = tt * 32;
    } else {
        const int tt = t - 42;
        W = uW2 + (size_t)l * 65536;
        dst = updW2T + ((size_t)l * 8 + tt) * TILE_SH;
        rowbase = tt * 32;
    }
    const int c = threadIdx.x;
    unsigned short buf[32];
    #pragma unroll
    for (int kk = 0; kk < 32; ++kk)
        buf[kk] = f2bu(W[(size_t)(rowbase + kk) * 256 + c]);
    #pragma unroll
    for (int j = 0; j < 4; ++j)
        *(s16x8*)&dst[(size_t)c * 32 + j * 8] = *(const s16x8*)&buf[j * 8];
}

// ---------------------------------------------------------------- k_lin
__global__ __launch_bounds__(256) void k_lin(const float* __restrict__ x,
                                             const float* __restrict__ W,
                                             const float* __restrict__ b,
                                             float* __restrict__ h) {
    __shared__ float Xs[16][68];
    const int tid = threadIdx.x;
    const int n0  = blockIdx.x * 16;
    {
        const int row = tid >> 4, q = tid & 15;
        const float4 v = *(const float4*)&x[(size_t)(n0 + row) * IN_DIM + q * 4];
        Xs[row][q * 4 + 0] = v.x; Xs[row][q * 4 + 1] = v.y;
        Xs[row][q * 4 + 2] = v.z; Xs[row][q * 4 + 3] = v.w;
    }
    __syncthreads();
    const int col = tid;
    float acc[16];
    #pragma unroll
    for (int r = 0; r < 16; ++r) acc[r] = 0.f;
    for (int k = 0; k < IN_DIM; ++k) {
        const float w = W[(size_t)k * HID + col];
        #pragma unroll
        for (int r = 0; r < 16; ++r) acc[r] += Xs[r][k] * w;
    }
    const float bb = b[col];
    #pragma unroll
    for (int r = 0; r < 16; ++r) h[(size_t)(n0 + r) * HID + col] = acc[r] + bb;
}

// ---------------------------------------------------------------- k_msg (MFMA, sorted edges)
// 64 sorted-by-dest edges x 256 cols per block; pipelined staging; run-length
// merged scatter (two 128-col halves through LDS reused as fp32).
__global__ __launch_bounds__(256, 2) void k_msg(const float* __restrict__ h,
                                                const float* __restrict__ sf,
                                                const float* __restrict__ ef,
                                                const float* __restrict__ ew,
                                                const int*   __restrict__ el,
                                                const int*   __restrict__ eidx,
                                                const unsigned short* __restrict__ W1T,
                                                const float* __restrict__ W1f,
                                                const float* __restrict__ b1,
                                                const unsigned short* __restrict__ W2T,
                                                const float* __restrict__ b2,
                                                float* __restrict__ upd) {
    __shared__ unsigned short As[64 * 40];
    __shared__ unsigned short Bs[256 * 40];
    __shared__ __align__(16) unsigned short Ts[64 * 264];   // also fp32 Mf[64][132]
    __shared__ int   Se[64], Sni[64], Sno[64];
    __shared__ float Sew[64], Ssa[64], Ssb[64];

    const int tid = threadIdx.x;
    const int e0  = blockIdx.x * 64;
    if (tid < 64) {
        const int e = eidx[e0 + tid];
        const int a = el[2 * e], bn = el[2 * e + 1];
        Se[tid] = e; Sni[tid] = a; Sno[tid] = bn;
        Sew[tid] = ew[e]; Ssa[tid] = sf[a]; Ssb[tid] = sf[bn];
    }
    __syncthreads();

    const int lane = tid & 63, wv = tid >> 6;
    const int lr = lane & 15, lq = lane >> 4;
    const int arow = tid & 63, aq = tid >> 6;
    const int ni = Sni[arow], no = Sno[arow], myE = Se[arow];

    f32x4 acc[4][4];
    #pragma unroll
    for (int i = 0; i < 4; ++i)
        #pragma unroll
        for (int j = 0; j < 4; ++j) acc[i][j] = (f32x4)(0.0f);

    float4 pvA0, pvA1;
    s16x8 pvB0, pvB1, pvB2, pvB3;

    // prefetch tile 0
    {
        const float* asrc = h + (size_t)ni * HID;
        pvA0 = *(const float4*)(asrc + aq * 8);
        pvA1 = *(const float4*)(asrc + aq * 8 + 4);
        const s16x8* srcB = (const s16x8*)(W1T + (size_t)tid * 32);
        pvB0 = srcB[0]; pvB1 = srcB[1]; pvB2 = srcB[2]; pvB3 = srcB[3];
    }

    // ---------------- GEMM1 : 18 K-steps ----------------
    for (int s = 0; s < 18; ++s) {
        __syncthreads();
        *(s16x8*)&As[arow * 40 + aq * 8] = pack8(pvA0, pvA1);
        {
            unsigned short* dst = &Bs[tid * 40];
            *(s16x8*)&dst[0]  = pvB0;
            *(s16x8*)&dst[8]  = pvB1;
            *(s16x8*)&dst[16] = pvB2;
            *(s16x8*)&dst[24] = pvB3;
        }
        __syncthreads();
        if (s + 1 < 18) {
            const int sn = s + 1;
            const float* asrc;
            if (sn < 8)       asrc = h  + (size_t)ni * HID + sn * 32;
            else if (sn < 16) asrc = h  + (size_t)no * HID + (sn - 8) * 32;
            else              asrc = ef + (size_t)myE * EDGE_DIM + (sn - 16) * 32;
            pvA0 = *(const float4*)(asrc + aq * 8);
            pvA1 = *(const float4*)(asrc + aq * 8 + 4);
            const s16x8* srcB = (const s16x8*)(W1T + (size_t)sn * TILE_SH + tid * 32);
            pvB0 = srcB[0]; pvB1 = srcB[1]; pvB2 = srcB[2]; pvB3 = srcB[3];
        }
        s16x8 af[4], bf[4];
        #pragma unroll
        for (int mf = 0; mf < 4; ++mf)
            af[mf] = *(const s16x8*)&As[(mf * 16 + lr) * 40 + lq * 8];
        #pragma unroll
        for (int nf = 0; nf < 4; ++nf)
            bf[nf] = *(const s16x8*)&Bs[(wv * 64 + nf * 16 + lr) * 40 + lq * 8];
        #pragma unroll
        for (int mf = 0; mf < 4; ++mf)
            #pragma unroll
            for (int nf = 0; nf < 4; ++nf)
                acc[mf][nf] = __builtin_amdgcn_mfma_f32_16x16x32_bf16(
                    af[mf], bf[nf], acc[mf][nf], 0, 0, 0);
    }

    // prefetch GEMM2 tile 0 (overlaps epilogue 1)
    {
        const s16x8* srcB = (const s16x8*)(W2T + (size_t)tid * 32);
        pvB0 = srcB[0]; pvB1 = srcB[1]; pvB2 = srcB[2]; pvB3 = srcB[3];
    }

    // epilogue 1: sf rank-1 + bias + relu -> Ts (bf16)
    #pragma unroll
    for (int nf = 0; nf < 4; ++nf) {
        const int col = wv * 64 + nf * 16 + lr;
        const float w512 = W1f[(size_t)512 * HID + col];
        const float w513 = W1f[(size_t)513 * HID + col];
        const float bb   = b1[col];
        #pragma unroll
        for (int mf = 0; mf < 4; ++mf)
            #pragma unroll
            for (int r = 0; r < 4; ++r) {
                const int row = mf * 16 + lq * 4 + r;
                float v = acc[mf][nf][r] + Ssa[row] * w512 + Ssb[row] * w513 + bb;
                Ts[row * 264 + col] = f2bu(fmaxf(v, 0.f));
            }
    }

    // ---------------- GEMM2 : 8 K-steps ----------------
    f32x4 acc2[4][4];
    #pragma unroll
    for (int i = 0; i < 4; ++i)
        #pragma unroll
        for (int j = 0; j < 4; ++j) acc2[i][j] = (f32x4)(0.0f);

    for (int s = 0; s < 8; ++s) {
        __syncthreads();
        {
            unsigned short* dst = &Bs[tid * 40];
            *(s16x8*)&dst[0]  = pvB0;
            *(s16x8*)&dst[8]  = pvB1;
            *(s16x8*)&dst[16] = pvB2;
            *(s16x8*)&dst[24] = pvB3;
        }
        __syncthreads();
        if (s + 1 < 8) {
            const s16x8* srcB = (const s16x8*)(W2T + (size_t)(s + 1) * TILE_SH + tid * 32);
            pvB0 = srcB[0]; pvB1 = srcB[1]; pvB2 = srcB[2]; pvB3 = srcB[3];
        }
        s16x8 af[4], bf[4];
        #pragma unroll
        for (int mf = 0; mf < 4; ++mf)
            af[mf] = *(const s16x8*)&Ts[(mf * 16 + lr) * 264 + s * 32 + lq * 8];
        #pragma unroll
        for (int nf = 0; nf < 4; ++nf)
            bf[nf] = *(const s16x8*)&Bs[(wv * 64 + nf * 16 + lr) * 40 + lq * 8];
        #pragma unroll
        for (int mf = 0; mf < 4; ++mf)
            #pragma unroll
            for (int nf = 0; nf < 4; ++nf)
                acc2[mf][nf] = __builtin_amdgcn_mfma_f32_16x16x32_bf16(
                    af[mf], bf[nf], acc2[mf][nf], 0, 0, 0);
    }

    // epilogue 2: run-length merged scatter, two 128-col halves via LDS (fp32)
    float* Mf = (float*)Ts;
    #pragma unroll
    for (int half = 0; half < 2; ++half) {
        __syncthreads();
        if ((wv >> 1) == half) {
            #pragma unroll
            for (int nf = 0; nf < 4; ++nf) {
                const int c  = (wv & 1) * 64 + nf * 16 + lr;   // col within half
                const float bb = b2[half * 128 + c];
                #pragma unroll
                for (int mf = 0; mf < 4; ++mf)
                    #pragma unroll
                    for (int r = 0; r < 4; ++r) {
                        const int row = mf * 16 + lq * 4 + r;
                        Mf[row * 132 + c] = (acc2[mf][nf][r] + bb) * Sew[row];
                    }
            }
        }
        __syncthreads();
        {
            const int c = tid & 127;
            const int colg = half * 128 + c;
            const int rbase = (tid >> 7) * 32;
            float a = 0.f;
            int cur = Sno[rbase];
            for (int r = rbase; r < rbase + 32; ++r) {
                const int g = Sno[r];
                if (g != cur) {
                    atomicAdd(&upd[(size_t)cur * HID + colg], a);
                    a = 0.f; cur = g;
                }
                a += Mf[r * 132 + c];
            }
            atomicAdd(&upd[(size_t)cur * HID + colg], a);
        }
    }
}

// ---------------------------------------------------------------- k_upd (MFMA, pipelined)
__global__ __launch_bounds__(256, 2) void k_upd(const float* __restrict__ h,
                                                const float* __restrict__ upd,
                                                const unsigned short* __restrict__ W1T,
                                                const float* __restrict__ b1,
                                                const unsigned short* __restrict__ W2T,
                                                const float* __restrict__ b2,
                                                float* __restrict__ hout) {
    __shared__ unsigned short As[64 * 40];
    __shared__ unsigned short Bs[256 * 40];
    __shared__ __align__(16) unsigned short Ts[64 * 264];

    const int tid = threadIdx.x;
    const int n0  = blockIdx.x * 64;
    const int lane = tid & 63, wv = tid >> 6;
    const int lr = lane & 15, lq = lane >> 4;
    const int arow = tid & 63, aq = tid >> 6;
    const int node = (n0 + arow < N_NODES) ? (n0 + arow) : (N_NODES - 1);

    f32x4 acc[4][4];
    #pragma unroll
    for (int i = 0; i < 4; ++i)
        #pragma unroll
        for (int j = 0; j < 4; ++j) acc[i][j] = (f32x4)(0.0f);

    float4 pvA0, pvA1;
    s16x8 pvB0, pvB1, pvB2, pvB3;
    {
        const float* asrc = h + (size_t)node * HID;
        pvA0 = *(const float4*)(asrc + aq * 8);
        pvA1 = *(const float4*)(asrc + aq * 8 + 4);
        const s16x8* srcB = (const s16x8*)(W1T + (size_t)tid * 32);
        pvB0 = srcB[0]; pvB1 = srcB[1]; pvB2 = srcB[2]; pvB3 = srcB[3];
    }

    for (int s = 0; s < 16; ++s) {
        __syncthreads();
        *(s16x8*)&As[arow * 40 + aq * 8] = pack8(pvA0, pvA1);
        {
            unsigned short* dst = &Bs[tid * 40];
            *(s16x8*)&dst[0]  = pvB0;
            *(s16x8*)&dst[8]  = pvB1;
            *(s16x8*)&dst[16] = pvB2;
            *(s16x8*)&dst[24] = pvB3;
        }
        __syncthreads();
        if (s + 1 < 16) {
            const int sn = s + 1;
            const float* asrc = (sn < 8) ? h   + (size_t)node * HID + sn * 32
                                         : upd + (size_t)node * HID + (sn - 8) * 32;
            pvA0 = *(const float4*)(asrc + aq * 8);
            pvA1 = *(const float4*)(asrc + aq * 8 + 4);
            const s16x8* srcB = (const s16x8*)(W1T + (size_t)sn * TILE_SH + tid * 32);
            pvB0 = srcB[0]; pvB1 = srcB[1]; pvB2 = srcB[2]; pvB3 = srcB[3];
        }
        s16x8 af[4], bf[4];
        #pragma unroll
        for (int mf = 0; mf < 4; ++mf)
            af[mf] = *(const s16x8*)&As[(mf * 16 + lr) * 40 + lq * 8];
        #pragma unroll
        for (int nf = 0; nf < 4; ++nf)
            bf[nf] = *(const s16x8*)&Bs[(wv * 64 + nf * 16 + lr) * 40 + lq * 8];
        #pragma unroll
        for (int mf = 0; mf < 4; ++mf)
            #pragma unroll
            for (int nf = 0; nf < 4; ++nf)
                acc[mf][nf] = __builtin_amdgcn_mfma_f32_16x16x32_bf16(
                    af[mf], bf[nf], acc[mf][nf], 0, 0, 0);
    }

    {
        const s16x8* srcB = (const s16x8*)(W2T + (size_t)tid * 32);
        pvB0 = srcB[0]; pvB1 = srcB[1]; pvB2 = srcB[2]; pvB3 = srcB[3];
    }

    #pragma unroll
    for (int nf = 0; nf < 4; ++nf) {
        const int col = wv * 64 + nf * 16 + lr;
        const float bb = b1[col];
        #pragma unroll
        for (int mf = 0; mf < 4; ++mf)
            #pragma unroll
            for (int r = 0; r < 4; ++r) {
                const int row = mf * 16 + lq * 4 + r;
                Ts[row * 264 + col] = f2bu(fmaxf(acc[mf][nf][r] + bb, 0.f));
            }
    }

    f32x4 acc2[4][4];
    #pragma unroll
    for (int i = 0; i < 4; ++i)
        #pragma unroll
        for (int j = 0; j < 4; ++j) acc2[i][j] = (f32x4)(0.0f);

    for (int s = 0; s < 8; ++s) {
        __syncthreads();
        {
            unsigned short* dst = &Bs[tid * 40];
            *(s16x8*)&dst[0]  = pvB0;
            *(s16x8*)&dst[8]  = pvB1;
            *(s16x8*)&dst[16] = pvB2;
            *(s16x8*)&dst[24] = pvB3;
        }
        __syncthreads();
        if (s + 1 < 8) {
            const s16x8* srcB = (const s16x8*)(W2T + (size_t)(s + 1) * TILE_SH + tid * 32);
            pvB0 = srcB[0]; pvB1 = srcB[1]; pvB2 = srcB[2]; pvB3 = srcB[3];
        }
        s16x8 af[4], bf[4];
        #pragma unroll
        for (int mf = 0; mf < 4; ++mf)
            af[mf] = *(const s16x8*)&Ts[(mf * 16 + lr) * 264 + s * 32 + lq * 8];
        #pragma unroll
        for (int nf = 0; nf < 4; ++nf)
            bf[nf] = *(const s16x8*)&Bs[(wv * 64 + nf * 16 + lr) * 40 + lq * 8];
        #pragma unroll
        for (int mf = 0; mf < 4; ++mf)
            #pragma unroll
            for (int nf = 0; nf < 4; ++nf)
                acc2[mf][nf] = __builtin_amdgcn_mfma_f32_16x16x32_bf16(
                    af[mf], bf[nf], acc2[mf][nf], 0, 0, 0);
    }

    #pragma unroll
    for (int nf = 0; nf < 4; ++nf) {
        const int col = wv * 64 + nf * 16 + lr;
        const float bb = b2[col];
        #pragma unroll
        for (int mf = 0; mf < 4; ++mf)
            #pragma unroll
            for (int r = 0; r < 4; ++r) {
                const int row = mf * 16 + lq * 4 + r;
                const int n = n0 + row;
                if (n < N_NODES)
                    hout[(size_t)n * HID + col] = fmaxf(acc2[mf][nf][r] + bb, 0.f);
            }
    }
}

// ---------------------------------------------------------------- k_graph
__global__ __launch_bounds__(256) void k_graph(const float* __restrict__ h,
                                               const int* __restrict__ n2g,
                                               float* __restrict__ out) {
    __shared__ int Sg[64];
    const int tid = threadIdx.x;
    const int n0  = blockIdx.x * 64;
    if (tid < 64) {
        const int n = n0 + tid;
        Sg[tid] = (n < N_NODES) ? n2g[n] : -1;
    }
    __syncthreads();
    const int col = tid;
    float accv = 0.f;
    int curg = Sg[0];
    for (int r = 0; r < 64; ++r) {
        const int n = n0 + r;
        if (n >= N_NODES) break;
        const int g = Sg[r];
        if (g != curg) {
            atomicAdd(&out[(size_t)curg * HID + col], accv);
            accv = 0.f; curg = g;
        }
        accv += h[(size_t)n * HID + col];
    }
    atomicAdd(&out[(size_t)curg * HID + col], accv);
}

// ---------------------------------------------------------------- launch
extern "C" void kernel_launch(void* const* d_in, const int* in_sizes, int n_in,
                              void* d_out, int out_size, void* d_ws, size_t ws_size,
                              hipStream_t stream) {
    const float* x    = (const float*)d_in[0];
    const float* sf   = (const float*)d_in[1];
    const float* ef   = (const float*)d_in[2];
    const float* ew   = (const float*)d_in[3];
    const int*   el   = (const int*)d_in[4];
    const int*   n2g  = (const int*)d_in[5];
    const float* Wlin = (const float*)d_in[6];
    const float* blin = (const float*)d_in[7];
    const float* mW1  = (const float*)d_in[8];
    const float* mb1  = (const float*)d_in[9];
    const float* mW2  = (const float*)d_in[10];
    const float* mb2  = (const float*)d_in[11];
    const float* uW1  = (const float*)d_in[12];
    const float* ub1  = (const float*)d_in[13];
    const float* uW2  = (const float*)d_in[14];
    const float* ub2  = (const float*)d_in[15];
    float* out = (float*)d_out;

    float* hA  = (float*)d_ws;                     // N_NODES*HID f32
    float* hB  = hA + (size_t)N_NODES * HID;
    float* upd = hB + (size_t)N_NODES * HID;
    unsigned short* wb = (unsigned short*)((char*)d_ws + (size_t)3 * N_NODES * HID * 4);
    unsigned short* msgW1T = wb;                                   // 3*18*8192
    unsigned short* msgW2T = msgW1T + (size_t)3 * 18 * TILE_SH;    // 3*8*8192
    unsigned short* updW1T = msgW2T + (size_t)3 * 8  * TILE_SH;    // 3*16*8192
    unsigned short* updW2T = updW1T + (size_t)3 * 16 * TILE_SH;    // 3*8*8192
    int* deg    = (int*)(updW2T + (size_t)3 * 8 * TILE_SH);
    int* off    = deg + N_NODES;
    int* cursor = off + N_NODES;
    int* eidx   = cursor + N_NODES;                                // N_EDGES

    hipMemsetAsync(d_out, 0, (size_t)NUM_GRAPHS * HID * sizeof(float), stream);
    hipMemsetAsync(deg, 0, (size_t)N_NODES * sizeof(int), stream);

    k_deg <<<(N_EDGES + 255) / 256, 256, 0, stream>>>(el, deg);
    k_scan<<<1, 256, 0, stream>>>(deg, off, cursor);
    k_scat<<<(N_EDGES + 255) / 256, 256, 0, stream>>>(el, cursor, eidx);

    k_prep<<<150, 256, 0, stream>>>(mW1, mW2, uW1, uW2,
                                    msgW1T, msgW2T, updW1T, updW2T);
    k_lin<<<N_NODES / 16, 256, 0, stream>>>(x, Wlin, blin, hA);

    float* hc = hA;
    float* hn = hB;
    for (int l = 0; l < N_LAYERS; ++l) {
        hipMemsetAsync(upd, 0, (size_t)N_NODES * HID * sizeof(float), stream);
        k_msg<<<N_EDGES / 64, 256, 0, stream>>>(
            hc, sf, ef, ew, el, eidx,
            msgW1T + (size_t)l * 18 * TILE_SH,
            mW1 + (size_t)l * 578 * 256, mb1 + (size_t)l * HID,
            msgW2T + (size_t)l * 8 * TILE_SH, mb2 + (size_t)l * HID, upd);
        k_upd<<<(N_NODES + 63) / 64, 256, 0, stream>>>(
            hc, upd,
            updW1T + (size_t)l * 16 * TILE_SH, ub1 + (size_t)l * HID,
            updW2T + (size_t)l * 8 * TILE_SH,  ub2 + (size_t)l * HID, hn);
        float* t = hc; hc = hn; hn = t;
    }

    k_graph<<<(N_NODES + 63) / 64, 256, 0, stream>>>(hc, n2g, out);
}

// Round 5
// 597.400 us; speedup vs baseline: 8.6547x; 1.2001x over previous
//
#include <hip/hip_runtime.h>
#include <hip/hip_bf16.h>

#define N_NODES   20000
#define N_EDGES   160000
#define IN_DIM    64
#define HID       256
#define EDGE_DIM  64
#define NUM_GRAPHS 128
#define N_LAYERS  3

typedef __attribute__((ext_vector_type(8))) short s16x8;
typedef __attribute__((ext_vector_type(4))) float f32x4;

static __device__ __forceinline__ unsigned short f2bu(float f) {
    union { __hip_bfloat16 h; unsigned short u; } cv;
    cv.h = __float2bfloat16(f);
    return cv.u;
}
static __device__ __forceinline__ s16x8 pack8(const float4 a, const float4 b) {
    s16x8 p;
    p[0] = (short)f2bu(a.x); p[1] = (short)f2bu(a.y);
    p[2] = (short)f2bu(a.z); p[3] = (short)f2bu(a.w);
    p[4] = (short)f2bu(b.x); p[5] = (short)f2bu(b.y);
    p[6] = (short)f2bu(b.z); p[7] = (short)f2bu(b.w);
    return p;
}

#define TILE_SH 8192   // [256 cols][32 k] bf16

// ---------------------------------------------------------------- sort kernels
__global__ __launch_bounds__(256) void k_deg(const int* __restrict__ el,
                                             int* __restrict__ deg) {
    const int e = blockIdx.x * 256 + threadIdx.x;
    if (e < N_EDGES) atomicAdd(&deg[el[2 * e + 1]], 1);
}

__global__ __launch_bounds__(256) void k_scan(const int* __restrict__ deg,
                                              int* __restrict__ off,
                                              int* __restrict__ cursor) {
    __shared__ int ts[256];
    const int t = threadIdx.x;
    const int base = t * 79;
    const int end  = (base + 79 < N_NODES) ? base + 79 : N_NODES;
    int s = 0;
    for (int i = base; i < end; ++i) s += deg[i];
    ts[t] = s;
    __syncthreads();
    for (int d = 1; d < 256; d <<= 1) {
        const int u = (t >= d) ? ts[t - d] : 0;
        __syncthreads();
        ts[t] += u;
        __syncthreads();
    }
    int run = (t == 0) ? 0 : ts[t - 1];
    for (int i = base; i < end; ++i) {
        off[i] = run; cursor[i] = run; run += deg[i];
    }
}

__global__ __launch_bounds__(256) void k_scat(const int* __restrict__ el,
                                              int* __restrict__ cursor,
                                              int* __restrict__ eidx) {
    const int e = blockIdx.x * 256 + threadIdx.x;
    if (e < N_EDGES) {
        const int d = el[2 * e + 1];
        const int p = atomicAdd(&cursor[d], 1);
        eidx[p] = e;
    }
}

// ---------------------------------------------------------------- k_prep
__global__ __launch_bounds__(256) void k_prep(const float* __restrict__ mW1,
                                              const float* __restrict__ mW2,
                                              const float* __restrict__ uW1,
                                              const float* __restrict__ uW2,
                                              unsigned short* __restrict__ msgW1T,
                                              unsigned short* __restrict__ msgW2T,
                                              unsigned short* __restrict__ updW1T,
                                              unsigned short* __restrict__ updW2T) {
    const int b = blockIdx.x;
    const int l = b / 50, t = b % 50;
    const float* W; unsigned short* dst; int rowbase;
    if (t < 18) {
        W = mW1 + (size_t)l * 578 * 256;
        dst = msgW1T + ((size_t)l * 18 + t) * TILE_SH;
        rowbase = (t < 16) ? t * 32 : 514 + (t - 16) * 32;
    } else if (t < 26) {
        const int tt = t - 18;
        W = mW2 + (size_t)l * 65536;
        dst = msgW2T + ((size_t)l * 8 + tt) * TILE_SH;
        rowbase = tt * 32;
    } else if (t < 42) {
        const int tt = t - 26;
        W = uW1 + (size_t)l * 131072;
        dst = updW1T + ((size_t)l * 16 + tt) * TILE_SH;
        rowbase = tt * 32;
    } else {
        const int tt = t - 42;
        W = uW2 + (size_t)l * 65536;
        dst = updW2T + ((size_t)l * 8 + tt) * TILE_SH;
        rowbase = tt * 32;
    }
    const int c = threadIdx.x;
    unsigned short buf[32];
    #pragma unroll
    for (int kk = 0; kk < 32; ++kk)
        buf[kk] = f2bu(W[(size_t)(rowbase + kk) * 256 + c]);
    #pragma unroll
    for (int j = 0; j < 4; ++j)
        *(s16x8*)&dst[(size_t)c * 32 + j * 8] = *(const s16x8*)&buf[j * 8];
}

// ---------------------------------------------------------------- k_lin
__global__ __launch_bounds__(256) void k_lin(const float* __restrict__ x,
                                             const float* __restrict__ W,
                                             const float* __restrict__ b,
                                             float* __restrict__ h) {
    __shared__ float Xs[16][68];
    const int tid = threadIdx.x;
    const int n0  = blockIdx.x * 16;
    {
        const int row = tid >> 4, q = tid & 15;
        const float4 v = *(const float4*)&x[(size_t)(n0 + row) * IN_DIM + q * 4];
        Xs[row][q * 4 + 0] = v.x; Xs[row][q * 4 + 1] = v.y;
        Xs[row][q * 4 + 2] = v.z; Xs[row][q * 4 + 3] = v.w;
    }
    __syncthreads();
    const int col = tid;
    float acc[16];
    #pragma unroll
    for (int r = 0; r < 16; ++r) acc[r] = 0.f;
    for (int k = 0; k < IN_DIM; ++k) {
        const float w = W[(size_t)k * HID + col];
        #pragma unroll
        for (int r = 0; r < 16; ++r) acc[r] += Xs[r][k] * w;
    }
    const float bb = b[col];
    #pragma unroll
    for (int r = 0; r < 16; ++r) h[(size_t)(n0 + r) * HID + col] = acc[r] + bb;
}

// ---------------------------------------------------------------- k_msg
// 64 sorted-by-dest edges x 256 cols. B fragments load DIRECTLY from global
// (prepacked tiles, L2-resident) — no LDS staging for B. A tile double-
// buffered in LDS -> 1 barrier per K-step. GEMM2 barrier-free.
__global__ __launch_bounds__(256, 3) void k_msg(const float* __restrict__ h,
                                                const float* __restrict__ sf,
                                                const float* __restrict__ ef,
                                                const float* __restrict__ ew,
                                                const int*   __restrict__ el,
                                                const int*   __restrict__ eidx,
                                                const unsigned short* __restrict__ W1T,
                                                const float* __restrict__ W1f,
                                                const float* __restrict__ b1,
                                                const unsigned short* __restrict__ W2T,
                                                const float* __restrict__ b2,
                                                float* __restrict__ upd) {
    __shared__ unsigned short As[2][64 * 40];
    __shared__ __align__(16) unsigned short Ts[64 * 264];   // also fp32 Mf[64][132]
    __shared__ int   Se[64], Sni[64], Sno[64];
    __shared__ float Sew[64], Ssa[64], Ssb[64];

    const int tid = threadIdx.x;
    const int e0  = blockIdx.x * 64;
    if (tid < 64) {
        const int e = eidx[e0 + tid];
        const int a = el[2 * e], bn = el[2 * e + 1];
        Se[tid] = e; Sni[tid] = a; Sno[tid] = bn;
        Sew[tid] = ew[e]; Ssa[tid] = sf[a]; Ssb[tid] = sf[bn];
    }
    __syncthreads();

    const int lane = tid & 63, wv = tid >> 6;
    const int lr = lane & 15, lq = lane >> 4;
    const int arow = tid & 63, aq = tid >> 6;
    const int ni = Sni[arow], no = Sno[arow], myE = Se[arow];

    const unsigned short* bp1 = W1T + ((size_t)(wv * 64 + lr)) * 32 + lq * 8;
    const unsigned short* bp2 = W2T + ((size_t)(wv * 64 + lr)) * 32 + lq * 8;

    f32x4 acc[4][4];
    #pragma unroll
    for (int i = 0; i < 4; ++i)
        #pragma unroll
        for (int j = 0; j < 4; ++j) acc[i][j] = (f32x4)(0.0f);

    // prologue: stage A(0), prefetch B(0)
    {
        const float* asrc = h + (size_t)ni * HID + aq * 8;
        const float4 a0 = *(const float4*)(asrc);
        const float4 a1 = *(const float4*)(asrc + 4);
        *(s16x8*)&As[0][arow * 40 + aq * 8] = pack8(a0, a1);
    }
    s16x8 bfr[4], nbr[4];
    #pragma unroll
    for (int nf = 0; nf < 4; ++nf)
        bfr[nf] = *(const s16x8*)(bp1 + nf * 512);
    __syncthreads();

    // ---------------- GEMM1 : 18 K-steps, 1 barrier each ----------------
    for (int s = 0; s < 18; ++s) {
        s16x8 af[4];
        #pragma unroll
        for (int mf = 0; mf < 4; ++mf)
            af[mf] = *(const s16x8*)&As[s & 1][(mf * 16 + lr) * 40 + lq * 8];
        const bool hasNext = (s + 1 < 18);
        float4 nA0, nA1;
        if (hasNext) {
            const int sn = s + 1;
            const float* asrc;
            if (sn < 8)       asrc = h  + (size_t)ni * HID + sn * 32;
            else if (sn < 16) asrc = h  + (size_t)no * HID + (sn - 8) * 32;
            else              asrc = ef + (size_t)myE * EDGE_DIM + (sn - 16) * 32;
            nA0 = *(const float4*)(asrc + aq * 8);
            nA1 = *(const float4*)(asrc + aq * 8 + 4);
            #pragma unroll
            for (int nf = 0; nf < 4; ++nf)
                nbr[nf] = *(const s16x8*)(bp1 + (size_t)sn * TILE_SH + nf * 512);
        }
        #pragma unroll
        for (int mf = 0; mf < 4; ++mf)
            #pragma unroll
            for (int nf = 0; nf < 4; ++nf)
                acc[mf][nf] = __builtin_amdgcn_mfma_f32_16x16x32_bf16(
                    af[mf], bfr[nf], acc[mf][nf], 0, 0, 0);
        if (hasNext) {
            *(s16x8*)&As[(s + 1) & 1][arow * 40 + aq * 8] = pack8(nA0, nA1);
            #pragma unroll
            for (int nf = 0; nf < 4; ++nf) bfr[nf] = nbr[nf];
            __syncthreads();
        }
    }

    // epilogue 1: sf rank-1 + bias + relu -> Ts (bf16)
    #pragma unroll
    for (int nf = 0; nf < 4; ++nf) {
        const int col = wv * 64 + nf * 16 + lr;
        const float w512 = W1f[(size_t)512 * HID + col];
        const float w513 = W1f[(size_t)513 * HID + col];
        const float bb   = b1[col];
        #pragma unroll
        for (int mf = 0; mf < 4; ++mf)
            #pragma unroll
            for (int r = 0; r < 4; ++r) {
                const int row = mf * 16 + lq * 4 + r;
                float v = acc[mf][nf][r] + Ssa[row] * w512 + Ssb[row] * w513 + bb;
                Ts[row * 264 + col] = f2bu(fmaxf(v, 0.f));
            }
    }
    __syncthreads();

    // ---------------- GEMM2 : 8 K-steps, barrier-free ----------------
    f32x4 acc2[4][4];
    #pragma unroll
    for (int i = 0; i < 4; ++i)
        #pragma unroll
        for (int j = 0; j < 4; ++j) acc2[i][j] = (f32x4)(0.0f);

    s16x8 b2f[4], n2b[4];
    #pragma unroll
    for (int nf = 0; nf < 4; ++nf)
        b2f[nf] = *(const s16x8*)(bp2 + nf * 512);

    for (int s = 0; s < 8; ++s) {
        s16x8 af[4];
        #pragma unroll
        for (int mf = 0; mf < 4; ++mf)
            af[mf] = *(const s16x8*)&Ts[(mf * 16 + lr) * 264 + s * 32 + lq * 8];
        if (s + 1 < 8) {
            #pragma unroll
            for (int nf = 0; nf < 4; ++nf)
                n2b[nf] = *(const s16x8*)(bp2 + (size_t)(s + 1) * TILE_SH + nf * 512);
        }
        #pragma unroll
        for (int mf = 0; mf < 4; ++mf)
            #pragma unroll
            for (int nf = 0; nf < 4; ++nf)
                acc2[mf][nf] = __builtin_amdgcn_mfma_f32_16x16x32_bf16(
                    af[mf], b2f[nf], acc2[mf][nf], 0, 0, 0);
        if (s + 1 < 8) {
            #pragma unroll
            for (int nf = 0; nf < 4; ++nf) b2f[nf] = n2b[nf];
        }
    }

    // epilogue 2: run-length merged scatter, two 128-col halves via LDS (fp32)
    float* Mf = (float*)Ts;
    #pragma unroll
    for (int half = 0; half < 2; ++half) {
        __syncthreads();
        if ((wv >> 1) == half) {
            #pragma unroll
            for (int nf = 0; nf < 4; ++nf) {
                const int c  = (wv & 1) * 64 + nf * 16 + lr;
                const float bb = b2[half * 128 + c];
                #pragma unroll
                for (int mf = 0; mf < 4; ++mf)
                    #pragma unroll
                    for (int r = 0; r < 4; ++r) {
                        const int row = mf * 16 + lq * 4 + r;
                        Mf[row * 132 + c] = (acc2[mf][nf][r] + bb) * Sew[row];
                    }
            }
        }
        __syncthreads();
        {
            const int c = tid & 127;
            const int colg = half * 128 + c;
            const int rbase = (tid >> 7) * 32;
            float a = 0.f;
            int cur = Sno[rbase];
            for (int r = rbase; r < rbase + 32; ++r) {
                const int g = Sno[r];
                if (g != cur) {
                    atomicAdd(&upd[(size_t)cur * HID + colg], a);
                    a = 0.f; cur = g;
                }
                a += Mf[r * 132 + c];
            }
            atomicAdd(&upd[(size_t)cur * HID + colg], a);
        }
    }
}

// ---------------------------------------------------------------- k_upd
__global__ __launch_bounds__(256, 3) void k_upd(const float* __restrict__ h,
                                                const float* __restrict__ upd,
                                                const unsigned short* __restrict__ W1T,
                                                const float* __restrict__ b1,
                                                const unsigned short* __restrict__ W2T,
                                                const float* __restrict__ b2,
                                                float* __restrict__ hout) {
    __shared__ unsigned short As[2][64 * 40];
    __shared__ __align__(16) unsigned short Ts[64 * 264];

    const int tid = threadIdx.x;
    const int n0  = blockIdx.x * 64;
    const int lane = tid & 63, wv = tid >> 6;
    const int lr = lane & 15, lq = lane >> 4;
    const int arow = tid & 63, aq = tid >> 6;
    const int node = (n0 + arow < N_NODES) ? (n0 + arow) : (N_NODES - 1);

    const unsigned short* bp1 = W1T + ((size_t)(wv * 64 + lr)) * 32 + lq * 8;
    const unsigned short* bp2 = W2T + ((size_t)(wv * 64 + lr)) * 32 + lq * 8;

    f32x4 acc[4][4];
    #pragma unroll
    for (int i = 0; i < 4; ++i)
        #pragma unroll
        for (int j = 0; j < 4; ++j) acc[i][j] = (f32x4)(0.0f);

    {
        const float* asrc = h + (size_t)node * HID + aq * 8;
        const float4 a0 = *(const float4*)(asrc);
        const float4 a1 = *(const float4*)(asrc + 4);
        *(s16x8*)&As[0][arow * 40 + aq * 8] = pack8(a0, a1);
    }
    s16x8 bfr[4], nbr[4];
    #pragma unroll
    for (int nf = 0; nf < 4; ++nf)
        bfr[nf] = *(const s16x8*)(bp1 + nf * 512);
    __syncthreads();

    for (int s = 0; s < 16; ++s) {
        s16x8 af[4];
        #pragma unroll
        for (int mf = 0; mf < 4; ++mf)
            af[mf] = *(const s16x8*)&As[s & 1][(mf * 16 + lr) * 40 + lq * 8];
        const bool hasNext = (s + 1 < 16);
        float4 nA0, nA1;
        if (hasNext) {
            const int sn = s + 1;
            const float* asrc = (sn < 8) ? h   + (size_t)node * HID + sn * 32
                                         : upd + (size_t)node * HID + (sn - 8) * 32;
            nA0 = *(const float4*)(asrc + aq * 8);
            nA1 = *(const float4*)(asrc + aq * 8 + 4);
            #pragma unroll
            for (int nf = 0; nf < 4; ++nf)
                nbr[nf] = *(const s16x8*)(bp1 + (size_t)sn * TILE_SH + nf * 512);
        }
        #pragma unroll
        for (int mf = 0; mf < 4; ++mf)
            #pragma unroll
            for (int nf = 0; nf < 4; ++nf)
                acc[mf][nf] = __builtin_amdgcn_mfma_f32_16x16x32_bf16(
                    af[mf], bfr[nf], acc[mf][nf], 0, 0, 0);
        if (hasNext) {
            *(s16x8*)&As[(s + 1) & 1][arow * 40 + aq * 8] = pack8(nA0, nA1);
            #pragma unroll
            for (int nf = 0; nf < 4; ++nf) bfr[nf] = nbr[nf];
            __syncthreads();
        }
    }

    #pragma unroll
    for (int nf = 0; nf < 4; ++nf) {
        const int col = wv * 64 + nf * 16 + lr;
        const float bb = b1[col];
        #pragma unroll
        for (int mf = 0; mf < 4; ++mf)
            #pragma unroll
            for (int r = 0; r < 4; ++r) {
                const int row = mf * 16 + lq * 4 + r;
                Ts[row * 264 + col] = f2bu(fmaxf(acc[mf][nf][r] + bb, 0.f));
            }
    }
    __syncthreads();

    f32x4 acc2[4][4];
    #pragma unroll
    for (int i = 0; i < 4; ++i)
        #pragma unroll
        for (int j = 0; j < 4; ++j) acc2[i][j] = (f32x4)(0.0f);

    s16x8 b2f[4], n2b[4];
    #pragma unroll
    for (int nf = 0; nf < 4; ++nf)
        b2f[nf] = *(const s16x8*)(bp2 + nf * 512);

    for (int s = 0; s < 8; ++s) {
        s16x8 af[4];
        #pragma unroll
        for (int mf = 0; mf < 4; ++mf)
            af[mf] = *(const s16x8*)&Ts[(mf * 16 + lr) * 264 + s * 32 + lq * 8];
        if (s + 1 < 8) {
            #pragma unroll
            for (int nf = 0; nf < 4; ++nf)
                n2b[nf] = *(const s16x8*)(bp2 + (size_t)(s + 1) * TILE_SH + nf * 512);
        }
        #pragma unroll
        for (int mf = 0; mf < 4; ++mf)
            #pragma unroll
            for (int nf = 0; nf < 4; ++nf)
                acc2[mf][nf] = __builtin_amdgcn_mfma_f32_16x16x32_bf16(
                    af[mf], b2f[nf], acc2[mf][nf], 0, 0, 0);
        if (s + 1 < 8) {
            #pragma unroll
            for (int nf = 0; nf < 4; ++nf) b2f[nf] = n2b[nf];
        }
    }

    #pragma unroll
    for (int nf = 0; nf < 4; ++nf) {
        const int col = wv * 64 + nf * 16 + lr;
        const float bb = b2[col];
        #pragma unroll
        for (int mf = 0; mf < 4; ++mf)
            #pragma unroll
            for (int r = 0; r < 4; ++r) {
                const int row = mf * 16 + lq * 4 + r;
                const int n = n0 + row;
                if (n < N_NODES)
                    hout[(size_t)n * HID + col] = fmaxf(acc2[mf][nf][r] + bb, 0.f);
            }
    }
}

// ---------------------------------------------------------------- k_graph
__global__ __launch_bounds__(256) void k_graph(const float* __restrict__ h,
                                               const int* __restrict__ n2g,
                                               float* __restrict__ out) {
    __shared__ int Sg[64];
    const int tid = threadIdx.x;
    const int n0  = blockIdx.x * 64;
    if (tid < 64) {
        const int n = n0 + tid;
        Sg[tid] = (n < N_NODES) ? n2g[n] : -1;
    }
    __syncthreads();
    const int col = tid;
    float accv = 0.f;
    int curg = Sg[0];
    for (int r = 0; r < 64; ++r) {
        const int n = n0 + r;
        if (n >= N_NODES) break;
        const int g = Sg[r];
        if (g != curg) {
            atomicAdd(&out[(size_t)curg * HID + col], accv);
            accv = 0.f; curg = g;
        }
        accv += h[(size_t)n * HID + col];
    }
    atomicAdd(&out[(size_t)curg * HID + col], accv);
}

// ---------------------------------------------------------------- launch
extern "C" void kernel_launch(void* const* d_in, const int* in_sizes, int n_in,
                              void* d_out, int out_size, void* d_ws, size_t ws_size,
                              hipStream_t stream) {
    const float* x    = (const float*)d_in[0];
    const float* sf   = (const float*)d_in[1];
    const float* ef   = (const float*)d_in[2];
    const float* ew   = (const float*)d_in[3];
    const int*   el   = (const int*)d_in[4];
    const int*   n2g  = (const int*)d_in[5];
    const float* Wlin = (const float*)d_in[6];
    const float* blin = (const float*)d_in[7];
    const float* mW1  = (const float*)d_in[8];
    const float* mb1  = (const float*)d_in[9];
    const float* mW2  = (const float*)d_in[10];
    const float* mb2  = (const float*)d_in[11];
    const float* uW1  = (const float*)d_in[12];
    const float* ub1  = (const float*)d_in[13];
    const float* uW2  = (const float*)d_in[14];
    const float* ub2  = (const float*)d_in[15];
    float* out = (float*)d_out;

    float* hA  = (float*)d_ws;                     // N_NODES*HID f32
    float* hB  = hA + (size_t)N_NODES * HID;
    float* upd = hB + (size_t)N_NODES * HID;
    unsigned short* wb = (unsigned short*)((char*)d_ws + (size_t)3 * N_NODES * HID * 4);
    unsigned short* msgW1T = wb;                                   // 3*18*8192
    unsigned short* msgW2T = msgW1T + (size_t)3 * 18 * TILE_SH;    // 3*8*8192
    unsigned short* updW1T = msgW2T + (size_t)3 * 8  * TILE_SH;    // 3*16*8192
    unsigned short* updW2T = updW1T + (size_t)3 * 16 * TILE_SH;    // 3*8*8192
    int* deg    = (int*)(updW2T + (size_t)3 * 8 * TILE_SH);
    int* off    = deg + N_NODES;
    int* cursor = off + N_NODES;
    int* eidx   = cursor + N_NODES;                                // N_EDGES

    hipMemsetAsync(d_out, 0, (size_t)NUM_GRAPHS * HID * sizeof(float), stream);
    hipMemsetAsync(deg, 0, (size_t)N_NODES * sizeof(int), stream);

    k_deg <<<(N_EDGES + 255) / 256, 256, 0, stream>>>(el, deg);
    k_scan<<<1, 256, 0, stream>>>(deg, off, cursor);
    k_scat<<<(N_EDGES + 255) / 256, 256, 0, stream>>>(el, cursor, eidx);

    k_prep<<<150, 256, 0, stream>>>(mW1, mW2, uW1, uW2,
                                    msgW1T, msgW2T, updW1T, updW2T);
    k_lin<<<N_NODES / 16, 256, 0, stream>>>(x, Wlin, blin, hA);

    float* hc = hA;
    float* hn = hB;
    for (int l = 0; l < N_LAYERS; ++l) {
        hipMemsetAsync(upd, 0, (size_t)N_NODES * HID * sizeof(float), stream);
        k_msg<<<N_EDGES / 64, 256, 0, stream>>>(
            hc, sf, ef, ew, el, eidx,
            msgW1T + (size_t)l * 18 * TILE_SH,
            mW1 + (size_t)l * 578 * 256, mb1 + (size_t)l * HID,
            msgW2T + (size_t)l * 8 * TILE_SH, mb2 + (size_t)l * HID, upd);
        k_upd<<<(N_NODES + 63) / 64, 256, 0, stream>>>(
            hc, upd,
            updW1T + (size_t)l * 16 * TILE_SH, ub1 + (size_t)l * HID,
            updW2T + (size_t)l * 8 * TILE_SH,  ub2 + (size_t)l * HID, hn);
        float* t = hc; hc = hn; hn = t;
    }

    k_graph<<<(N_NODES + 63) / 64, 256, 0, stream>>>(hc, n2g, out);
}